// Round 14
// baseline (13744.070 us; speedup 1.0000x reference)
//
#include <hip/hip_runtime.h>

// Farthest point sampling, B=32, N=32768, npoint=4096.
// R14: force packed f32 math via inline VOP3P asm (R13's ext_vector float2
// was scalarized by clang; 18 inst/pt measured vs ~7 essential).
//  - per 2-pt chunk: 3x v_pk_add_f32(neg) + 1x v_pk_mul_f32 + 2x v_pk_fma_f32
//    == bit-exact d = fmaf(dz,dz, fmaf(dx,dx, dy*dy)) per half.
//  - NT=1024 (4 waves/SIMD: R13's 2 waves/SIMD leaked 36% to latency).
//  - pair ownership g = c*2048 + 2*tid + j, z in dynamic LDS, ds_read_b64.
//  - 3-slot rotating LDS atomicMax reduce, ONE barrier/step (R12, proven).
//  - argmax tracks 5-bit local id lc=2c+j (ascends with global index ->
//    numpy first-occurrence preserved); global idx rebuilt once per step.
// PASSING arithmetic (R6, bit-exact), contract(off). Output float32:
// [B*NPOINT] idx, [B*NPOINT*3] coords.

#define BATCH  32
#define NPTS   32768
#define NPOINT 4096
#define NT     1024
#define NCH    16            // chunks of 2: 32 points per thread
#define SMEM_BYTES (NPTS * 4 + 32)

typedef float f32x2 __attribute__((ext_vector_type(2)));

__global__ __launch_bounds__(NT, 1) void fps_kernel(
    const float* __restrict__ xyz,   // [B, N, 3] float32
    float* __restrict__ out_idx,     // [B, NPOINT]
    float* __restrict__ out_xyz)     // [B, NPOINT, 3]
{
#pragma clang fp contract(off)
    extern __shared__ char smem[];
    float* pz_lds = (float*)smem;                                // NPTS floats
    unsigned long long* s_key = (unsigned long long*)(smem + NPTS * 4); // [3]

    const int b   = blockIdx.x;
    const int tid = threadIdx.x;
    const float* base = xyz + (size_t)b * NPTS * 3;

    f32x2 px2[NCH], py2[NCH], dist2[NCH];
#pragma unroll
    for (int c = 0; c < NCH; ++c) {
#pragma unroll
        for (int j = 0; j < 2; ++j) {
            const int g = c * 2048 + 2 * tid + j;
            px2[c][j] = base[g * 3 + 0];
            py2[c][j] = base[g * 3 + 1];
            pz_lds[g] = base[g * 3 + 2];
            dist2[c][j] = 1e10f;
        }
    }
    if (tid == 0) { s_key[0] = 0ull; s_key[1] = 0ull; s_key[2] = 0ull; }
    __syncthreads();                       // pz_lds + slots ready

    int w = 1;   // RAN=False seed
    int p = 0;   // rotating slot index k%3

    for (int k = 0; k < NPOINT; ++k) {
        // Broadcast centroid from global (same addr across lanes, L2-hot).
        const float cx = base[w * 3 + 0];
        const float cy = base[w * 3 + 1];
        const float cz = base[w * 3 + 2];
        if (tid == 0) {
            out_idx[(size_t)b * NPOINT + k] = (float)w;
            float* o = out_xyz + ((size_t)b * NPOINT + k) * 3;
            o[0] = cx; o[1] = cy; o[2] = cz;
        }
        const f32x2 cx2 = { cx, cx };
        const f32x2 cy2 = { cy, cy };
        const f32x2 cz2 = { cz, cz };

        // Distance update + first-occurrence argmax over 32 points.
        float best = -1.0f;
        int   lc   = 63;    // invalid-high; any real candidate wins via >
#pragma unroll
        for (int c = 0; c < NCH; ++c) {
            const f32x2 zz = *(const f32x2*)&pz_lds[c * 2048 + 2 * tid];
            f32x2 d2, t1;
            // Packed (2 pts/inst), bit-exact per half:
            //   d = fma(dz,dz, fma(dx,dx, dy*dy)), subs = pk_add with neg.
            asm("v_pk_add_f32 %0, %2, %5 neg_lo:[0,1] neg_hi:[0,1]\n\t"
                "v_pk_add_f32 %1, %3, %6 neg_lo:[0,1] neg_hi:[0,1]\n\t"
                "v_pk_mul_f32 %1, %1, %1\n\t"
                "v_pk_fma_f32 %1, %0, %0, %1\n\t"
                "v_pk_add_f32 %0, %4, %7 neg_lo:[0,1] neg_hi:[0,1]\n\t"
                "v_pk_fma_f32 %0, %0, %0, %1"
                : "=&v"(d2), "=&v"(t1)
                : "v"(px2[c]), "v"(py2[c]), "v"(zz),
                  "v"(cx2), "v"(cy2), "v"(cz2));
#pragma unroll
            for (int j = 0; j < 2; ++j) {
                const float nd = fminf(dist2[c][j], d2[j]);
                dist2[c][j] = nd;
                if (nd > best) { best = nd; lc = 2 * c + j; }
            }
        }
        // Reconstruct global index: g = (lc>>1)*2048 + 2*tid + (lc&1).
        int bi = (lc >> 1) * 2048 + 2 * tid + (lc & 1);

        // Wave (64-lane) butterfly argmax; ties -> smaller index.
#pragma unroll
        for (int off = 1; off < 64; off <<= 1) {
            const float ov = __shfl_xor(best, off, 64);
            const int   oi = __shfl_xor(bi,   off, 64);
            if (ov > best || (ov == best && oi < bi)) { best = ov; bi = oi; }
        }

        // 16 wave leaders -> LDS atomicMax on packed key, slot p = k%3.
        if ((tid & 63) == 0) {
            const unsigned long long myk =
                ((unsigned long long)__float_as_uint(best) << 32) |
                (unsigned int)(~bi);
            atomicMax(&s_key[p], myk);
        }
        __syncthreads();                   // winner published
        const unsigned long long kk = s_key[p];
        // Reset slot for step k+2 (next step's barrier orders this write
        // before that step's atomicMax; its readers finished at step k-1).
        const int pn2 = (p >= 1) ? (p - 1) : 2;   // (k+2)%3
        if (tid == 0) s_key[pn2] = 0ull;
        w = (int)(~(unsigned int)kk);      // low word = ~idx
        p = (p == 2) ? 0 : (p + 1);
    }
}

extern "C" void kernel_launch(void* const* d_in, const int* in_sizes, int n_in,
                              void* d_out, int out_size, void* d_ws, size_t ws_size,
                              hipStream_t stream) {
    const float* xyz = (const float*)d_in[0];
    float* out = (float*)d_out;
    float* out_idx = out;                              // B*NPOINT floats
    float* out_xyz = out + (size_t)BATCH * NPOINT;     // B*NPOINT*3 floats

    // Opt into >64KB dynamic LDS (runtime call, not captured by graphs).
    (void)hipFuncSetAttribute((const void*)fps_kernel,
                              hipFuncAttributeMaxDynamicSharedMemorySize,
                              SMEM_BYTES);

    fps_kernel<<<BATCH, NT, SMEM_BYTES, stream>>>(xyz, out_idx, out_xyz);
}

// Round 15
// 11252.303 us; speedup vs baseline: 1.2214x; 1.2214x over previous
//
#include <hip/hip_runtime.h>

// Farthest point sampling, B=32, N=32768, npoint=4096.
// R15: make the state FIT the 64-arch-VGPR class instead of fighting the
// allocator (R10-R14: 1024-thread blocks always get 64 arch VGPRs; the
// 96-float state went to AGPRs, ~2.5x VALU issue inflation from copies).
//  - 2 blocks per batch (64 blocks), 16 pts/thread: px/py/dist = 48 floats
//    + temps ~ 62 regs -> arch-resident, no v_accvgpr traffic.
//  - z-half (16384 pts) in 64KB dynamic LDS, pair ds_read_b64 (R10 proven).
//  - per-step cross-block agree, minimal protocol: fresh 8B slot per
//    (step, block) in d_ws; leader release-stores packed key
//    (f32bits(dist)<<32 | ~idx), acquire-polls partner slot (key != 0
//    guaranteed: low word ~idx >= 0xFFFF8000), max-combines locally.
//    No RMW, no counters. Pair = bid^32 -> same XCD (32 % 8 == 0) -> polls
//    are local-L2. Slots zeroed by captured hipMemsetAsync each launch;
//    winner = max -> replay-deterministic. 64 blocks always co-resident.
//  - in-block reduce: wave butterfly + 3-slot rotating LDS atomicMax
//    (R12 proven), ties -> smaller global index (numpy first-occurrence;
//    halves have disjoint idx ranges so cross-half ties resolve via ~idx).
// PASSING arithmetic (R6, bit-exact): d = fmaf(dz,dz, fmaf(dx,dx, dy*dy)),
// contract(off), fminf chain, ascending-index strict-> argmax.
// Output float32: [B*NPOINT] idx, [B*NPOINT*3] coords.

#define BATCH  32
#define NPTS   32768
#define NPOINT 4096
#define NT     1024
#define HALF   16384
#define NCH    8              // chunks of 2: 16 points per thread
#define NBLK   64
#define SMEM_BYTES (HALF * 4 + 64)
#define WS_NEEDED ((size_t)NPOINT * NBLK * 8)

__global__ __launch_bounds__(NT, 1) void fps_pair(
    const float* __restrict__ xyz,   // [B, N, 3] float32
    float* __restrict__ out_idx,     // [B, NPOINT]
    float* __restrict__ out_xyz,     // [B, NPOINT, 3]
    unsigned long long* __restrict__ ex)   // [NPOINT][NBLK], zeroed
{
#pragma clang fp contract(off)
    extern __shared__ char smem[];
    float* pz_lds = (float*)smem;                                 // HALF floats
    unsigned long long* s_key = (unsigned long long*)(smem + HALF * 4); // [3]
    int* s_w = (int*)(smem + HALF * 4 + 24);

    const int bid = blockIdx.x;
    const int g   = bid & (BATCH - 1);   // batch
    const int h   = bid >> 5;            // half 0/1; partner = bid ^ 32
    const int tid = threadIdx.x;
    const float* base = xyz + (size_t)g * NPTS * 3;
    const int goff = h * HALF;

    float px[NCH * 2], py[NCH * 2], dist[NCH * 2];
#pragma unroll
    for (int c = 0; c < NCH; ++c) {
#pragma unroll
        for (int j = 0; j < 2; ++j) {
            const int i  = c * 2 + j;
            const int gl = c * 2048 + 2 * tid + j;      // local [0,16384)
            const int gg = goff + gl;                   // global [0,32768)
            px[i] = base[gg * 3 + 0];
            py[i] = base[gg * 3 + 1];
            pz_lds[gl] = base[gg * 3 + 2];
            dist[i] = 1e10f;
        }
    }
    if (tid == 0) { s_key[0] = 0ull; s_key[1] = 0ull; s_key[2] = 0ull; }
    __syncthreads();                       // pz_lds + slots ready

    int w = 1;   // RAN=False seed
    int p = 0;   // rotating slot index k%3

    for (int k = 0; k < NPOINT; ++k) {
        // Broadcast centroid from global (same addr across lanes, L2-hot).
        const float cx = base[w * 3 + 0];
        const float cy = base[w * 3 + 1];
        const float cz = base[w * 3 + 2];
        if (h == 0 && tid == 0) {
            out_idx[(size_t)g * NPOINT + k] = (float)w;
            float* o = out_xyz + ((size_t)g * NPOINT + k) * 3;
            o[0] = cx; o[1] = cy; o[2] = cz;
        }
        if (k == NPOINT - 1) break;

        // Distance update + first-occurrence argmax over my 16 points.
        // Local id lc = 2c+j ascends with global index -> strict > keeps
        // the first max (numpy semantics).
        float best = -1.0f;
        int   lc   = 31;
#pragma unroll
        for (int c = 0; c < NCH; ++c) {
            const float2 zz = *(const float2*)&pz_lds[c * 2048 + 2 * tid];
            const float pzv[2] = { zz.x, zz.y };
#pragma unroll
            for (int j = 0; j < 2; ++j) {
                const int i = c * 2 + j;
                const float dx = px[i] - cx;
                const float dy = py[i] - cy;
                const float dz = pzv[j] - cz;
                const float d  = fmaf(dz, dz, fmaf(dx, dx, dy * dy));
                const float nd = fminf(dist[i], d);
                dist[i] = nd;
                if (nd > best) { best = nd; lc = 2 * c + j; }
            }
        }
        int bi = goff + (lc >> 1) * 2048 + 2 * tid + (lc & 1);

        // Wave (64-lane) butterfly argmax; ties -> smaller index.
#pragma unroll
        for (int off = 1; off < 64; off <<= 1) {
            const float ov = __shfl_xor(best, off, 64);
            const int   oi = __shfl_xor(bi,   off, 64);
            if (ov > best || (ov == best && oi < bi)) { best = ov; bi = oi; }
        }

        // 16 wave leaders -> LDS atomicMax on packed key, slot p = k%3.
        if ((tid & 63) == 0) {
            const unsigned long long myk =
                ((unsigned long long)__float_as_uint(best) << 32) |
                (unsigned int)(~bi);
            atomicMax(&s_key[p], myk);
        }
        __syncthreads();                   // B1: block winner published

        if (tid == 0) {
            const unsigned long long kk = s_key[p];
            const int pn2 = (p >= 1) ? (p - 1) : 2;   // (k+2)%3
            s_key[pn2] = 0ull;             // reset slot for step k+2
            // Cross-block exchange on fresh per-step slots (same XCD).
            unsigned long long* slot = ex + (size_t)k * NBLK;
            __hip_atomic_store(&slot[bid], kk, __ATOMIC_RELEASE,
                               __HIP_MEMORY_SCOPE_AGENT);
            unsigned long long pk;
            do {
                pk = __hip_atomic_load(&slot[bid ^ 32], __ATOMIC_ACQUIRE,
                                       __HIP_MEMORY_SCOPE_AGENT);
            } while (pk == 0ull);          // key always nonzero (low=~idx)
            const unsigned long long win = (kk > pk) ? kk : pk;
            *s_w = (int)(~(unsigned int)win);
        }
        __syncthreads();                   // B2: combined winner ready
        w = *s_w;
        p = (p == 2) ? 0 : (p + 1);
    }
}

// ---------- fallback (R10, passing 12.7ms): if ws too small ----------
#define FB_NCH 16
#define FB_SMEM (NPTS * 4 + 32)

__global__ __launch_bounds__(NT, 1) void fps_single(
    const float* __restrict__ xyz, float* __restrict__ out_idx,
    float* __restrict__ out_xyz)
{
#pragma clang fp contract(off)
    extern __shared__ char smem[];
    float* pz_lds = (float*)smem;
    unsigned long long* s_key = (unsigned long long*)(smem + NPTS * 4);
    const int b = blockIdx.x, tid = threadIdx.x;
    const float* base = xyz + (size_t)b * NPTS * 3;
    float px[FB_NCH * 2], py[FB_NCH * 2], dist[FB_NCH * 2];
#pragma unroll
    for (int c = 0; c < FB_NCH; ++c) {
#pragma unroll
        for (int j = 0; j < 2; ++j) {
            const int i = c * 2 + j, gg = c * 2048 + 2 * tid + j;
            px[i] = base[gg * 3 + 0]; py[i] = base[gg * 3 + 1];
            pz_lds[gg] = base[gg * 3 + 2]; dist[i] = 1e10f;
        }
    }
    if (tid == 0) { s_key[0] = 0ull; s_key[1] = 0ull; s_key[2] = 0ull; }
    __syncthreads();
    int w = 1, p = 0;
    for (int k = 0; k < NPOINT; ++k) {
        const float cx = base[w * 3 + 0], cy = base[w * 3 + 1],
                    cz = base[w * 3 + 2];
        if (tid == 0) {
            out_idx[(size_t)b * NPOINT + k] = (float)w;
            float* o = out_xyz + ((size_t)b * NPOINT + k) * 3;
            o[0] = cx; o[1] = cy; o[2] = cz;
        }
        float best = -1.0f; int lc = 63;
#pragma unroll
        for (int c = 0; c < FB_NCH; ++c) {
            const float2 zz = *(const float2*)&pz_lds[c * 2048 + 2 * tid];
            const float pzv[2] = { zz.x, zz.y };
#pragma unroll
            for (int j = 0; j < 2; ++j) {
                const int i = c * 2 + j;
                const float dx = px[i] - cx, dy = py[i] - cy,
                            dz = pzv[j] - cz;
                const float d  = fmaf(dz, dz, fmaf(dx, dx, dy * dy));
                const float nd = fminf(dist[i], d);
                dist[i] = nd;
                if (nd > best) { best = nd; lc = 2 * c + j; }
            }
        }
        int bi = (lc >> 1) * 2048 + 2 * tid + (lc & 1);
#pragma unroll
        for (int off = 1; off < 64; off <<= 1) {
            const float ov = __shfl_xor(best, off, 64);
            const int   oi = __shfl_xor(bi,   off, 64);
            if (ov > best || (ov == best && oi < bi)) { best = ov; bi = oi; }
        }
        if ((tid & 63) == 0) {
            const unsigned long long myk =
                ((unsigned long long)__float_as_uint(best) << 32) |
                (unsigned int)(~bi);
            atomicMax(&s_key[p], myk);
        }
        __syncthreads();
        const unsigned long long kk = s_key[p];
        const int pn2 = (p >= 1) ? (p - 1) : 2;
        if (tid == 0) s_key[pn2] = 0ull;
        w = (int)(~(unsigned int)kk);
        p = (p == 2) ? 0 : (p + 1);
    }
}

extern "C" void kernel_launch(void* const* d_in, const int* in_sizes, int n_in,
                              void* d_out, int out_size, void* d_ws, size_t ws_size,
                              hipStream_t stream) {
    const float* xyz = (const float*)d_in[0];
    float* out = (float*)d_out;
    float* out_idx = out;                              // B*NPOINT floats
    float* out_xyz = out + (size_t)BATCH * NPOINT;     // B*NPOINT*3 floats

    if (ws_size >= WS_NEEDED) {
        unsigned long long* ex = (unsigned long long*)d_ws;
        hipMemsetAsync(d_ws, 0, WS_NEEDED, stream);    // fresh slots / replay
        (void)hipFuncSetAttribute((const void*)fps_pair,
                                  hipFuncAttributeMaxDynamicSharedMemorySize,
                                  SMEM_BYTES);
        fps_pair<<<NBLK, NT, SMEM_BYTES, stream>>>(xyz, out_idx, out_xyz, ex);
    } else {
        (void)hipFuncSetAttribute((const void*)fps_single,
                                  hipFuncAttributeMaxDynamicSharedMemorySize,
                                  FB_SMEM);
        fps_single<<<BATCH, NT, FB_SMEM, stream>>>(xyz, out_idx, out_xyz);
    }
}